// Round 6
// baseline (38.859 us; speedup 1.0000x reference)
//
#include <hip/hip_runtime.h>

#define HH   48
#define WW   96
#define CC   256
#define RRAD 4
#define DD   9
#define DD2  81
#define PP   10
#define HWSZ (HH * WW)              // 4608
#define ROWB 512                    // bytes per bf16 channel row (256*2)
#define ZOFF ((unsigned)HWSZ * ROWB) // zero page offset from f2tb base

typedef __attribute__((ext_vector_type(8))) short short8v;  // 8 bf16 (4 VGPRs)
typedef __attribute__((ext_vector_type(4))) float f32x4;

__device__ __forceinline__ unsigned bf16rne(float f) {      // RNE f32->bf16 bits
  unsigned u = __float_as_uint(f);
  return (u + 0x7FFFu + ((u >> 16) & 1u)) >> 16;
}

// async global->LDS, 16B per lane; LDS dest wave-uniform base + lane*16 (linear),
// global src per-lane (gather). Counted by vmcnt; __syncthreads drains it.
__device__ __forceinline__ void gload_lds16(const char* g, char* l) {
  __builtin_amdgcn_global_load_lds(
      (const __attribute__((address_space(1))) char*)g,
      (__attribute__((address_space(3))) char*)l, 16, 0, 0);
}

// ---------------- kernel 1: (C,H,W) fp32 -> (H*W, 256ch) bf16, both inputs ----------------
__global__ __launch_bounds__(256) void transpose_to_bf16(
    const float* __restrict__ f1, const float* __restrict__ f2,
    char* __restrict__ f2tb, char* __restrict__ f1tb, char* __restrict__ zpage) {
  __shared__ float tile[64][65];
  const float* src = (blockIdx.y == 0) ? f1 : f2;
  char* dst = (blockIdx.y == 0) ? f1tb : f2tb;

  const int tid = threadIdx.x;
  if (blockIdx.y == 0 && blockIdx.x == 0 && tid < 32) {   // zero the 512 B zero page
    float4 z = {0.f, 0.f, 0.f, 0.f};
    *(float4*)(zpage + tid * 16) = z;
  }

  const int tiles_p = HWSZ / 64;              // 72
  const int bc = blockIdx.x / tiles_p;        // channel tile 0..3
  const int bp = blockIdx.x % tiles_p;        // pixel tile 0..71
  const int c0 = bc * 64, p0 = bp * 64;

#pragma unroll
  for (int k = 0; k < 16; k++) {
    int idx = k * 256 + tid;
    int cl = idx >> 6, pl = idx & 63;         // coalesced over pixels
    tile[cl][pl] = src[(size_t)(c0 + cl) * HWSZ + p0 + pl];
  }
  __syncthreads();
#pragma unroll
  for (int k = 0; k < 8; k++) {               // pack 2 channels -> 4 B stores
    int idx = k * 256 + tid;
    int pl = idx >> 5, cp = idx & 31;
    unsigned lo = bf16rne(tile[2 * cp][pl]);
    unsigned hi = bf16rne(tile[2 * cp + 1][pl]);
    *(unsigned*)(dst + (size_t)(p0 + pl) * ROWB + (size_t)c0 * 2 + cp * 4) =
        lo | (hi << 16);
  }
}

// ---------------- kernel 2: global_load_lds-staged MFMA correlation + DAP ----------------
// LDS 52 KB -> 3 blocks/CU; __launch_bounds__(256,3) -> VGPR cap ~170.
__global__ __launch_bounds__(256, 3) void corr_main(
    const char* __restrict__ f2tb, const char* __restrict__ f1tb,
    const float* __restrict__ coords, const float* __restrict__ w_dap,
    float* __restrict__ out) {
  __shared__ __align__(16) char patch[100 * ROWB];  // 51200 B
  __shared__ unsigned rowoff[100];            // source byte offset (ZOFF = zero page)
  __shared__ float dots[112];
  __shared__ float corrs[DD2];
  float* partial = (float*)patch;             // aliases patch (dead after MFMA phase)

  const int p = blockIdx.x;                   // pixel h*W+w
  const int tid = threadIdx.x;

  const float cx = coords[p];
  const float cy = coords[HWSZ + p];
  const float fxf = floorf(cx), fyf = floorf(cy);
  const float fx = cx - fxf, fy = cy - fyf;   // fractional weights shared by all 81 offsets
  const int xb = (int)fxf - RRAD;
  const int yb = (int)fyf - RRAD;

  if (tid < 100) {
    int yy = tid / 10, xx = tid - yy * 10;
    int gy = yb + yy, gx = xb + xx;
    rowoff[tid] = (gx >= 0 && gx < WW && gy >= 0 && gy < HH)
                      ? (unsigned)(gy * WW + gx) * ROWB : ZOFF;
  }

  const int lane = tid & 63, wid = tid >> 6;
  const int hi = lane >> 4, lo = lane & 15;

  // B fragments: f1 vector (same for all 16 cols); k = hi*8 + j within ktile kt
  const char* f1b = f1tb + (size_t)p * ROWB + hi * 16;
  short8v bfrag[8];
#pragma unroll
  for (int kt = 0; kt < 8; kt++) bfrag[kt] = *(const short8v*)(f1b + kt * 64);

  __syncthreads();                            // rowoff ready

  // stage 100 rows (50 KB-instrs, 2 rows each) via global_load_lds.
  // LDS linear dest; bank-swizzle achieved by PRE-SWIZZLING the global source:
  // LDS[r*512 + x] = G[r][x ^ ((r&7)<<4)]  (involution, applied again on read).
  {
    const int sub = lane >> 5;                // which of the 2 rows in this KB
    const int col = (lane & 31) * 16;         // byte within row
    for (int s = wid; s < 50; s += 4) {
      const int r = 2 * s + sub;
      const unsigned ro = rowoff[r];
      const char* src = f2tb + ro + (col ^ ((r & 7) << 4));
      gload_lds16(src, &patch[s * 1024]);
    }
  }
  __syncthreads();                            // drains vmcnt (staging complete)

  // 7 m-tiles of 16 patch rows; A-fragments from swizzled LDS (2-way banks = free)
#pragma unroll
  for (int mi = 0; mi < 2; mi++) {
    const int m = wid + mi * 4;
    if (m < 7) {
      int row = m * 16 + lo;
      row = row > 99 ? 99 : row;              // tile-6 tail: dup row, discarded
      const char* rp = patch + row * ROWB;
      const int swz = (row & 7) << 4;
      short8v a[8];
#pragma unroll
      for (int kt = 0; kt < 8; kt++)
        a[kt] = *(const short8v*)(rp + ((hi * 16 + kt * 64) ^ swz));
      f32x4 acc = {0.f, 0.f, 0.f, 0.f};
#pragma unroll
      for (int kt = 0; kt < 8; kt++)
        acc = __builtin_amdgcn_mfma_f32_16x16x32_bf16(a[kt], bfrag[kt], acc, 0, 0, 0);
      // D: col = lo, row = hi*4 + j; keep col 0 only
      if (lo == 0) {
        const int rb = m * 16 + hi * 4;
        dots[rb + 0] = acc[0];
        dots[rb + 1] = acc[1];
        dots[rb + 2] = acc[2];
        dots[rb + 3] = acc[3];
      }
    }
  }
  __syncthreads();

  // 81 bilinear combines; d = i*9 + j (i = x-offset idx, j = y-offset idx)
  if (tid < DD2) {
    const int i = tid / DD, j = tid - i * DD;
    const float d00 = dots[j * PP + i];
    const float d01 = dots[j * PP + i + 1];
    const float d10 = dots[(j + 1) * PP + i];
    const float d11 = dots[(j + 1) * PP + i + 1];
    const float c = (1.f - fy) * ((1.f - fx) * d00 + fx * d01) +
                    fy * ((1.f - fx) * d10 + fx * d11);
    corrs[tid] = c * 0.0625f;                 // 1/sqrt(256)
  }
  __syncthreads();

  // DAP: out[o] = sum_d w_dap[o,d] * corrs[d]; partial aliases dead patch buffer
  if (tid < 243) {
    const int o = tid % DD2, chunk = tid / DD2;
    const int d0 = chunk * 27;
    float acc = 0.f;
#pragma unroll
    for (int d = 0; d < 27; d++) acc += w_dap[o * DD2 + d0 + d] * corrs[d0 + d];
    partial[chunk * DD2 + o] = acc;
  }
  __syncthreads();
  if (tid < DD2) {
    out[(size_t)tid * HWSZ + p] =
        partial[tid] + partial[DD2 + tid] + partial[2 * DD2 + tid];
  }
}

extern "C" void kernel_launch(void* const* d_in, const int* in_sizes, int n_in,
                              void* d_out, int out_size, void* d_ws, size_t ws_size,
                              hipStream_t stream) {
  const float* f1     = (const float*)d_in[0];
  const float* f2     = (const float*)d_in[1];
  const float* coords = (const float*)d_in[2];
  const float* w_dap  = (const float*)d_in[3];
  float* out = (float*)d_out;

  // ws layout: [f2tb: HWSZ*512 B][zpage: 512 B][f1tb: HWSZ*512 B]
  char* f2tb  = (char*)d_ws;
  char* zpage = f2tb + (size_t)HWSZ * ROWB;
  char* f1tb  = zpage + 512;

  dim3 tgrid((CC / 64) * (HWSZ / 64), 2);
  transpose_to_bf16<<<tgrid, 256, 0, stream>>>(f1, f2, f2tb, f1tb, zpage);

  corr_main<<<dim3(HWSZ), 256, 0, stream>>>(f2tb, f1tb, coords, w_dap, out);
}